// Round 4
// baseline (159.804 us; speedup 1.0000x reference)
//
#include <hip/hip_runtime.h>
#include <hip/hip_bf16.h>

// B=1, NN=256, C=128, H=4, D=32 — O(N^3) factorization, single persistent kernel.
//   w = x @ W_w (256x512); a,b,c,v head slices at col offsets 0,128,256,384
//   P = exp(s a b^T), Q = exp(s a c^T), R = exp(s b c^T)   (s = 1/sqrt(32))
//   T = P R ;  normp[h][ib][k] = partial sum_i Q[i,k] T[i,k]  (deterministic)
//   rn[k] = 1/clip(sum_ib normp, 1e-6)
//   S[i,j] = sum_k Q[i,k] R[j,k] rn[k]
//   x1 = (P.*S) v ; x2 = (Q.*T.*rn) v ; y = x1.*x2
//   out = y @ W_proj + b_proj

constexpr size_t OFF_W     = 0;                    // 256*512
constexpr size_t OFF_P     = 131072;               // 4*65536 each
constexpr size_t OFF_Q     = OFF_P + 262144;
constexpr size_t OFF_R     = OFF_Q + 262144;
constexpr size_t OFF_S     = OFF_R + 262144;
constexpr size_t OFF_T     = OFF_S + 262144;
constexpr size_t OFF_NORMP = OFF_T + 262144;       // 4*8*256 = 8192
constexpr size_t OFF_Y     = OFF_NORMP + 8192;     // 256*128
constexpr size_t OFF_BAR   = OFF_Y + 32768;        // 8 barriers * 16 uints

__device__ __forceinline__ void gridbar(unsigned* bar, int idx) {
    __syncthreads();
    if (threadIdx.x == 0) {
        __threadfence();
        unsigned* c = bar + idx * 16;
        __hip_atomic_fetch_add(c, 1u, __ATOMIC_ACQ_REL, __HIP_MEMORY_SCOPE_AGENT);
        while (__hip_atomic_load(c, __ATOMIC_ACQUIRE, __HIP_MEMORY_SCOPE_AGENT) < 256u) {
            __builtin_amdgcn_s_sleep(2);
        }
    }
    __syncthreads();
}

__global__ __launch_bounds__(256) void k_mega(
    const float* __restrict__ x, const float* __restrict__ Ww,
    const float* __restrict__ Wproj, const float* __restrict__ bproj,
    float* __restrict__ ws, float* __restrict__ out) {

    __shared__ float smem[12544];  // 49 KB

    float* w     = ws + OFF_W;
    float* P     = ws + OFF_P;
    float* Q     = ws + OFF_Q;
    float* R     = ws + OFF_R;
    float* S     = ws + OFF_S;
    float* T     = ws + OFF_T;
    float* normp = ws + OFF_NORMP;
    float* y     = ws + OFF_Y;
    unsigned* bar = (unsigned*)(ws + OFF_BAR);

    const int bid = blockIdx.x;
    const int t = threadIdx.x;
    const int tx = t & 15, ty = t >> 4;   // 16x16 compute grid
    const int r = t >> 3, g = t & 7;      // 32x8 staging grid

    float* As = smem;          // [32][36], layout [k][i]
    float* Bs = smem + 1152;   // [32][36], layout [k][j]

    // ================= phase 1: w = x @ Ww (blocks 0..127) =================
    if (bid < 128) {
        int i0 = (bid >> 4) * 32, j0 = (bid & 15) * 32;
        float a00 = 0, a01 = 0, a10 = 0, a11 = 0;
        for (int kc = 0; kc < 128; kc += 32) {
            float4 a4 = *(const float4*)&x[(size_t)(i0 + r) * 128 + kc + g * 4];
            As[(g * 4 + 0) * 36 + r] = a4.x; As[(g * 4 + 1) * 36 + r] = a4.y;
            As[(g * 4 + 2) * 36 + r] = a4.z; As[(g * 4 + 3) * 36 + r] = a4.w;
            *(float4*)&Bs[r * 36 + g * 4] =
                *(const float4*)&Ww[(size_t)(kc + r) * 512 + j0 + g * 4];
            __syncthreads();
#pragma unroll
            for (int kk = 0; kk < 32; kk++) {
                float2 av = *(float2*)&As[kk * 36 + ty * 2];
                float2 bv = *(float2*)&Bs[kk * 36 + tx * 2];
                a00 += av.x * bv.x; a01 += av.x * bv.y;
                a10 += av.y * bv.x; a11 += av.y * bv.y;
            }
            __syncthreads();
        }
        *(float2*)&w[(size_t)(i0 + ty * 2) * 512 + j0 + tx * 2] = make_float2(a00, a01);
        *(float2*)&w[(size_t)(i0 + ty * 2 + 1) * 512 + j0 + tx * 2] = make_float2(a10, a11);
    }
    gridbar(bar, 0);

    // ================= phase 2: P,Q,R (all 256 blocks) =================
    {
        int h = bid >> 6, r0 = ((bid >> 3) & 7) * 32, s0 = (bid & 7) * 32;
        float* aR = smem;
        float* bR = smem + 1152;
        float* bS = smem + 2304;
        float* cS = smem + 3456;
        *(float4*)&aR[r * 36 + g * 4] =
            *(const float4*)&w[(size_t)(r0 + r) * 512 + h * 32 + g * 4];
        *(float4*)&bR[r * 36 + g * 4] =
            *(const float4*)&w[(size_t)(r0 + r) * 512 + 128 + h * 32 + g * 4];
        *(float4*)&bS[r * 36 + g * 4] =
            *(const float4*)&w[(size_t)(s0 + r) * 512 + 128 + h * 32 + g * 4];
        *(float4*)&cS[r * 36 + g * 4] =
            *(const float4*)&w[(size_t)(s0 + r) * 512 + 256 + h * 32 + g * 4];
        __syncthreads();
        float dab[2][2] = {}, dac[2][2] = {}, dbc[2][2] = {};
#pragma unroll
        for (int d = 0; d < 32; d += 2) {
            float2 a0 = *(float2*)&aR[(ty * 2) * 36 + d];
            float2 a1 = *(float2*)&aR[(ty * 2 + 1) * 36 + d];
            float2 p0 = *(float2*)&bR[(ty * 2) * 36 + d];
            float2 p1 = *(float2*)&bR[(ty * 2 + 1) * 36 + d];
            float2 b0 = *(float2*)&bS[(tx * 2) * 36 + d];
            float2 b1 = *(float2*)&bS[(tx * 2 + 1) * 36 + d];
            float2 c0 = *(float2*)&cS[(tx * 2) * 36 + d];
            float2 c1 = *(float2*)&cS[(tx * 2 + 1) * 36 + d];
            dab[0][0] += a0.x * b0.x + a0.y * b0.y; dab[0][1] += a0.x * b1.x + a0.y * b1.y;
            dab[1][0] += a1.x * b0.x + a1.y * b0.y; dab[1][1] += a1.x * b1.x + a1.y * b1.y;
            dac[0][0] += a0.x * c0.x + a0.y * c0.y; dac[0][1] += a0.x * c1.x + a0.y * c1.y;
            dac[1][0] += a1.x * c0.x + a1.y * c0.y; dac[1][1] += a1.x * c1.x + a1.y * c1.y;
            dbc[0][0] += p0.x * c0.x + p0.y * c0.y; dbc[0][1] += p0.x * c1.x + p0.y * c1.y;
            dbc[1][0] += p1.x * c0.x + p1.y * c0.y; dbc[1][1] += p1.x * c1.x + p1.y * c1.y;
        }
        const float sc = 0.17677669529663687f;
        size_t hb = (size_t)h * 65536;
#pragma unroll
        for (int rr = 0; rr < 2; rr++) {
            size_t o = hb + (size_t)(r0 + ty * 2 + rr) * 256 + s0 + tx * 2;
            *(float2*)&P[o] = make_float2(__expf(sc * dab[rr][0]), __expf(sc * dab[rr][1]));
            *(float2*)&Q[o] = make_float2(__expf(sc * dac[rr][0]), __expf(sc * dac[rr][1]));
            *(float2*)&R[o] = make_float2(__expf(sc * dbc[rr][0]), __expf(sc * dbc[rr][1]));
        }
    }
    gridbar(bar, 1);

    // ================= phase 3: T = P R, normp partials =================
    {
        int h = bid >> 6, i0 = ((bid >> 3) & 7) * 32, k0 = (bid & 7) * 32;
        size_t hb = (size_t)h * 65536;
        float a00 = 0, a01 = 0, a10 = 0, a11 = 0;
        for (int jc = 0; jc < 256; jc += 32) {
            float4 a4 = *(const float4*)&P[hb + (size_t)(i0 + r) * 256 + jc + g * 4];
            As[(g * 4 + 0) * 36 + r] = a4.x; As[(g * 4 + 1) * 36 + r] = a4.y;
            As[(g * 4 + 2) * 36 + r] = a4.z; As[(g * 4 + 3) * 36 + r] = a4.w;
            *(float4*)&Bs[r * 36 + g * 4] =
                *(const float4*)&R[hb + (size_t)(jc + r) * 256 + k0 + g * 4];
            __syncthreads();
#pragma unroll
            for (int kk = 0; kk < 32; kk++) {
                float2 av = *(float2*)&As[kk * 36 + ty * 2];
                float2 bv = *(float2*)&Bs[kk * 36 + tx * 2];
                a00 += av.x * bv.x; a01 += av.x * bv.y;
                a10 += av.y * bv.x; a11 += av.y * bv.y;
            }
            __syncthreads();
        }
        size_t o0 = hb + (size_t)(i0 + ty * 2) * 256 + k0 + tx * 2;
        size_t o1 = o0 + 256;
        *(float2*)&T[o0] = make_float2(a00, a01);
        *(float2*)&T[o1] = make_float2(a10, a11);
        float2 q0 = *(const float2*)&Q[o0];
        float2 q1 = *(const float2*)&Q[o1];
        float* red = smem + 2304;  // [16][34]
        red[ty * 34 + tx * 2]     = q0.x * a00 + q1.x * a10;
        red[ty * 34 + tx * 2 + 1] = q0.y * a01 + q1.y * a11;
        __syncthreads();
        if (t < 32) {
            float s = 0.f;
#pragma unroll
            for (int m = 0; m < 16; m++) s += red[m * 34 + t];
            normp[h * 2048 + (i0 >> 5) * 256 + k0 + t] = s;
        }
    }
    gridbar(bar, 2);

    // ================= phase 4: S = Q (R rn)^T =================
    {
        int h = bid >> 6, i0 = ((bid >> 3) & 7) * 32, j0 = (bid & 7) * 32;
        size_t hb = (size_t)h * 65536;
        float* rn_s = smem + 2304;  // [256]
        {
            float s = 0.f;
#pragma unroll
            for (int ib = 0; ib < 8; ib++) s += normp[h * 2048 + ib * 256 + t];
            rn_s[t] = 1.f / fmaxf(s, 1e-6f);
        }
        __syncthreads();
        float a00 = 0, a01 = 0, a10 = 0, a11 = 0;
        for (int kc = 0; kc < 256; kc += 32) {
            float4 a4 = *(const float4*)&Q[hb + (size_t)(i0 + r) * 256 + kc + g * 4];
            As[(g * 4 + 0) * 36 + r] = a4.x; As[(g * 4 + 1) * 36 + r] = a4.y;
            As[(g * 4 + 2) * 36 + r] = a4.z; As[(g * 4 + 3) * 36 + r] = a4.w;
            float4 b4 = *(const float4*)&R[hb + (size_t)(j0 + r) * 256 + kc + g * 4];
            b4.x *= rn_s[kc + g * 4 + 0]; b4.y *= rn_s[kc + g * 4 + 1];
            b4.z *= rn_s[kc + g * 4 + 2]; b4.w *= rn_s[kc + g * 4 + 3];
            Bs[(g * 4 + 0) * 36 + r] = b4.x; Bs[(g * 4 + 1) * 36 + r] = b4.y;
            Bs[(g * 4 + 2) * 36 + r] = b4.z; Bs[(g * 4 + 3) * 36 + r] = b4.w;
            __syncthreads();
#pragma unroll
            for (int kk = 0; kk < 32; kk++) {
                float2 av = *(float2*)&As[kk * 36 + ty * 2];
                float2 bv = *(float2*)&Bs[kk * 36 + tx * 2];
                a00 += av.x * bv.x; a01 += av.x * bv.y;
                a10 += av.y * bv.x; a11 += av.y * bv.y;
            }
            __syncthreads();
        }
        *(float2*)&S[hb + (size_t)(i0 + ty * 2) * 256 + j0 + tx * 2] = make_float2(a00, a01);
        *(float2*)&S[hb + (size_t)(i0 + ty * 2 + 1) * 256 + j0 + tx * 2] = make_float2(a10, a11);
    }
    gridbar(bar, 3);

    // ================= phase 5: x1,x2,y (blocks 0..127) =================
    if (bid < 128) {
        int h = bid >> 5, i0 = (bid & 31) * 8;
        size_t hb = (size_t)h * 65536;
        float* wp = smem;            // [8][256]
        float* wq = smem + 2048;     // [8][256]
        float* vls = smem + 4096;    // [256][32]
        float* rn_s = smem + 12288;  // [256]
        {
            float s = 0.f;
#pragma unroll
            for (int ib = 0; ib < 8; ib++) s += normp[h * 2048 + ib * 256 + t];
            rn_s[t] = 1.f / fmaxf(s, 1e-6f);
        }
        __syncthreads();
#pragma unroll
        for (int m = 0; m < 2; m++) {
            int lin = (m * 256 + t) * 4;
            int rr = lin >> 8, jj = lin & 255;
            size_t o = hb + (size_t)(i0 + rr) * 256 + jj;
            float4 p4 = *(const float4*)&P[o];
            float4 s4 = *(const float4*)&S[o];
            float4 q4 = *(const float4*)&Q[o];
            float4 t4 = *(const float4*)&T[o];
            float4 wpv, wqv;
            wpv.x = p4.x * s4.x; wpv.y = p4.y * s4.y;
            wpv.z = p4.z * s4.z; wpv.w = p4.w * s4.w;
            wqv.x = q4.x * t4.x * rn_s[jj + 0]; wqv.y = q4.y * t4.y * rn_s[jj + 1];
            wqv.z = q4.z * t4.z * rn_s[jj + 2]; wqv.w = q4.w * t4.w * rn_s[jj + 3];
            *(float4*)&wp[rr * 256 + jj] = wpv;
            *(float4*)&wq[rr * 256 + jj] = wqv;
        }
#pragma unroll
        for (int m = 0; m < 8; m++) {
            int lin = (m * 256 + t) * 4;
            int jj = lin >> 5, dd = lin & 31;
            *(float4*)&vls[jj * 32 + dd] =
                *(const float4*)&w[(size_t)jj * 512 + 384 + h * 32 + dd];
        }
        __syncthreads();
        int d = t & 31, rl = t >> 5;
        float x1 = 0.f, x2 = 0.f;
#pragma unroll 8
        for (int j = 0; j < 256; j++) {
            float vv = vls[j * 32 + d];
            x1 += wp[rl * 256 + j] * vv;
            x2 += wq[rl * 256 + j] * vv;
        }
        y[(size_t)(i0 + rl) * 128 + h * 32 + d] = x1 * x2;
    }
    gridbar(bar, 4);

    // ================= phase 6: out = y @ Wproj + b (blocks 0..31) =================
    if (bid < 32) {
        int i0 = (bid >> 2) * 32, j0 = (bid & 3) * 32;
        float a00 = 0, a01 = 0, a10 = 0, a11 = 0;
        for (int kc = 0; kc < 128; kc += 32) {
            float4 a4 = *(const float4*)&y[(size_t)(i0 + r) * 128 + kc + g * 4];
            As[(g * 4 + 0) * 36 + r] = a4.x; As[(g * 4 + 1) * 36 + r] = a4.y;
            As[(g * 4 + 2) * 36 + r] = a4.z; As[(g * 4 + 3) * 36 + r] = a4.w;
            *(float4*)&Bs[r * 36 + g * 4] =
                *(const float4*)&Wproj[(size_t)(kc + r) * 128 + j0 + g * 4];
            __syncthreads();
#pragma unroll
            for (int kk = 0; kk < 32; kk++) {
                float2 av = *(float2*)&As[kk * 36 + ty * 2];
                float2 bv = *(float2*)&Bs[kk * 36 + tx * 2];
                a00 += av.x * bv.x; a01 += av.x * bv.y;
                a10 += av.y * bv.x; a11 += av.y * bv.y;
            }
            __syncthreads();
        }
        float b0 = bproj[j0 + tx * 2], b1 = bproj[j0 + tx * 2 + 1];
        *(float2*)&out[(size_t)(i0 + ty * 2) * 128 + j0 + tx * 2] =
            make_float2(a00 + b0, a01 + b1);
        *(float2*)&out[(size_t)(i0 + ty * 2 + 1) * 128 + j0 + tx * 2] =
            make_float2(a10 + b0, a11 + b1);
    }
}

extern "C" void kernel_launch(void* const* d_in, const int* in_sizes, int n_in,
                              void* d_out, int out_size, void* d_ws, size_t ws_size,
                              hipStream_t stream) {
    const float* x      = (const float*)d_in[0];
    const float* W_w    = (const float*)d_in[1];
    const float* W_proj = (const float*)d_in[2];
    const float* b_proj = (const float*)d_in[3];
    float* out = (float*)d_out;
    float* ws  = (float*)d_ws;

    // zero the grid-barrier counters (graph-replay-safe init)
    hipMemsetAsync(ws + OFF_BAR, 0, 8 * 16 * sizeof(unsigned), stream);
    k_mega<<<dim3(256), dim3(256), 0, stream>>>(x, W_w, W_proj, b_proj, ws, out);
}

// Round 5
// 48.000 us; speedup vs baseline: 3.3292x; 3.3292x over previous
//
#include <hip/hip_runtime.h>
#include <hip/hip_bf16.h>

// B=1, NN=256, C=128, H=4, D=32 — O(N^3) factorization, 5 kernels.
//   w = x @ W_w (256x512); a,b,c,v head slices at col offsets 0,128,256,384
//   P = exp(s a b^T), Q = exp(s a c^T), R = exp(s b c^T)   (s = 1/sqrt(32))
//   k_T computes P,R on the fly per j-chunk, accumulates T = P R,
//       side-writes Q (all blocks), P (k0==0 blocks), R^T (i0==0 blocks),
//       and deterministic norm partials normp[h][i-block][k].
//   rn[k] = 1/clip(sum normp, 1e-6)
//   S[i,j] = sum_k (Q[i,k] rn[k]) Rt[k,j]
//   x1 = (P.*S) v ; x2 = (Q.*T.*rn) v ; y = x1.*x2
//   out = y @ W_proj + b_proj

constexpr size_t OFF_W     = 0;                    // 256*512
constexpr size_t OFF_P     = 131072;               // 4*65536 each
constexpr size_t OFF_Q     = OFF_P + 262144;
constexpr size_t OFF_RT    = OFF_Q + 262144;       // R^T: [h][k][j]
constexpr size_t OFF_S     = OFF_RT + 262144;
constexpr size_t OFF_T     = OFF_S + 262144;
constexpr size_t OFF_NORMP = OFF_T + 262144;       // 4*8*256
constexpr size_t OFF_Y     = OFF_NORMP + 8192;     // 256*128

// ---- K1: w = x(256x128) @ Ww(128x512), 32x32 tile, prefetch dbuf ----
__global__ __launch_bounds__(256) void k_w(const float* __restrict__ x,
                                           const float* __restrict__ Ww,
                                           float* __restrict__ w) {
    __shared__ __align__(16) float As[1152];  // [k][i]
    __shared__ __align__(16) float Bs[1152];  // [k][j]
    int j0 = blockIdx.x * 32, i0 = blockIdx.y * 32;
    int t = threadIdx.x, tx = t & 15, ty = t >> 4, r = t >> 3, g = t & 7;
    float4 a4 = *(const float4*)&x[(size_t)(i0 + r) * 128 + g * 4];
    float4 b4 = *(const float4*)&Ww[(size_t)r * 512 + j0 + g * 4];
    float a00 = 0, a01 = 0, a10 = 0, a11 = 0;
    for (int kc = 0; kc < 128; kc += 32) {
        As[(g * 4 + 0) * 36 + r] = a4.x; As[(g * 4 + 1) * 36 + r] = a4.y;
        As[(g * 4 + 2) * 36 + r] = a4.z; As[(g * 4 + 3) * 36 + r] = a4.w;
        *(float4*)&Bs[r * 36 + g * 4] = b4;
        __syncthreads();
        if (kc + 32 < 128) {
            a4 = *(const float4*)&x[(size_t)(i0 + r) * 128 + kc + 32 + g * 4];
            b4 = *(const float4*)&Ww[(size_t)(kc + 32 + r) * 512 + j0 + g * 4];
        }
#pragma unroll
        for (int kk = 0; kk < 32; kk++) {
            float2 av = *(float2*)&As[kk * 36 + ty * 2];
            float2 bv = *(float2*)&Bs[kk * 36 + tx * 2];
            a00 += av.x * bv.x; a01 += av.x * bv.y;
            a10 += av.y * bv.x; a11 += av.y * bv.y;
        }
        __syncthreads();
    }
    *(float2*)&w[(size_t)(i0 + ty * 2) * 512 + j0 + tx * 2] = make_float2(a00, a01);
    *(float2*)&w[(size_t)(i0 + ty * 2 + 1) * 512 + j0 + tx * 2] = make_float2(a10, a11);
}

// ---- K2: fused PQR + T + normp. grid (8,8,4). ----
__global__ __launch_bounds__(256) void k_T(const float* __restrict__ w,
                                           float* __restrict__ P,
                                           float* __restrict__ Q,
                                           float* __restrict__ Rt,
                                           float* __restrict__ T,
                                           float* __restrict__ normp) {
    __shared__ __align__(16) float aT[1152];  // [d][i]
    __shared__ __align__(16) float cT[1152];  // [d][k]
    __shared__ __align__(16) float bT[1152];  // [d][j]
    __shared__ __align__(16) float Ps[1152];  // [j][i]
    __shared__ __align__(16) float Rs[1152];  // [j][k]
    int h = blockIdx.z, k0 = blockIdx.x * 32, i0 = blockIdx.y * 32;
    size_t hb = (size_t)h * 65536;
    int t = threadIdx.x, tx = t & 15, ty = t >> 4, r = t >> 3, g = t & 7;
    const float sc = 0.17677669529663687f;

    float4 av = *(const float4*)&w[(size_t)(i0 + r) * 512 + h * 32 + g * 4];
    aT[(g * 4 + 0) * 36 + r] = av.x; aT[(g * 4 + 1) * 36 + r] = av.y;
    aT[(g * 4 + 2) * 36 + r] = av.z; aT[(g * 4 + 3) * 36 + r] = av.w;
    float4 cv = *(const float4*)&w[(size_t)(k0 + r) * 512 + 256 + h * 32 + g * 4];
    cT[(g * 4 + 0) * 36 + r] = cv.x; cT[(g * 4 + 1) * 36 + r] = cv.y;
    cT[(g * 4 + 2) * 36 + r] = cv.z; cT[(g * 4 + 3) * 36 + r] = cv.w;
    // prefetch first b chunk
    float4 bv = *(const float4*)&w[(size_t)r * 512 + 128 + h * 32 + g * 4];
    __syncthreads();

    // Q tile: i = 2ty+ii, k = 2tx+kk
    float dq00 = 0, dq01 = 0, dq10 = 0, dq11 = 0;
#pragma unroll
    for (int d = 0; d < 32; d++) {
        float2 a2 = *(float2*)&aT[d * 36 + ty * 2];
        float2 c2 = *(float2*)&cT[d * 36 + tx * 2];
        dq00 += a2.x * c2.x; dq01 += a2.x * c2.y;
        dq10 += a2.y * c2.x; dq11 += a2.y * c2.y;
    }
    float q00 = __expf(sc * dq00), q01 = __expf(sc * dq01);
    float q10 = __expf(sc * dq10), q11 = __expf(sc * dq11);
    *(float2*)&Q[hb + (size_t)(i0 + ty * 2) * 256 + k0 + tx * 2] = make_float2(q00, q01);
    *(float2*)&Q[hb + (size_t)(i0 + ty * 2 + 1) * 256 + k0 + tx * 2] = make_float2(q10, q11);

    const bool wP = (k0 == 0), wR = (i0 == 0);
    float acc00 = 0, acc01 = 0, acc10 = 0, acc11 = 0;
    for (int jc = 0; jc < 256; jc += 32) {
        // stage b chunk (safe: prior readers of bT passed barrier B)
        bT[(g * 4 + 0) * 36 + r] = bv.x; bT[(g * 4 + 1) * 36 + r] = bv.y;
        bT[(g * 4 + 2) * 36 + r] = bv.z; bT[(g * 4 + 3) * 36 + r] = bv.w;
        __syncthreads();  // A: bT ready, prior T-accum (Ps/Rs reads) done
        if (jc + 32 < 256)
            bv = *(const float4*)&w[(size_t)(jc + 32 + r) * 512 + 128 + h * 32 + g * 4];
        // P chunk (j=2ty+jj, i=2tx+ii) and R chunk (j=2ty+jj, k=2tx+kk), share b reads
        float dp00 = 0, dp01 = 0, dp10 = 0, dp11 = 0;
        float dr00 = 0, dr01 = 0, dr10 = 0, dr11 = 0;
#pragma unroll
        for (int d = 0; d < 32; d++) {
            float2 b2 = *(float2*)&bT[d * 36 + ty * 2];
            float2 a2 = *(float2*)&aT[d * 36 + tx * 2];
            float2 c2 = *(float2*)&cT[d * 36 + tx * 2];
            dp00 += b2.x * a2.x; dp01 += b2.x * a2.y;
            dp10 += b2.y * a2.x; dp11 += b2.y * a2.y;
            dr00 += b2.x * c2.x; dr01 += b2.x * c2.y;
            dr10 += b2.y * c2.x; dr11 += b2.y * c2.y;
        }
        float p00 = __expf(sc * dp00), p01 = __expf(sc * dp01);
        float p10 = __expf(sc * dp10), p11 = __expf(sc * dp11);
        float r00 = __expf(sc * dr00), r01 = __expf(sc * dr01);
        float r10 = __expf(sc * dr10), r11 = __expf(sc * dr11);
        *(float2*)&Ps[(ty * 2 + 0) * 36 + tx * 2] = make_float2(p00, p01);
        *(float2*)&Ps[(ty * 2 + 1) * 36 + tx * 2] = make_float2(p10, p11);
        *(float2*)&Rs[(ty * 2 + 0) * 36 + tx * 2] = make_float2(r00, r01);
        *(float2*)&Rs[(ty * 2 + 1) * 36 + tx * 2] = make_float2(r10, r11);
        if (wP) {  // P[i][j], i = i0+2tx+ii, j-pair = jc+2ty
            *(float2*)&P[hb + (size_t)(i0 + tx * 2 + 0) * 256 + jc + ty * 2] = make_float2(p00, p10);
            *(float2*)&P[hb + (size_t)(i0 + tx * 2 + 1) * 256 + jc + ty * 2] = make_float2(p01, p11);
        }
        if (wR) {  // Rt[k][j], k = k0+2tx+kk, j-pair = jc+2ty
            *(float2*)&Rt[hb + (size_t)(k0 + tx * 2 + 0) * 256 + jc + ty * 2] = make_float2(r00, r10);
            *(float2*)&Rt[hb + (size_t)(k0 + tx * 2 + 1) * 256 + jc + ty * 2] = make_float2(r01, r11);
        }
        __syncthreads();  // B: Ps/Rs ready
        // T accumulate: i = 2ty+ii, k = 2tx+kk
#pragma unroll
        for (int j = 0; j < 32; j++) {
            float2 p2 = *(float2*)&Ps[j * 36 + ty * 2];
            float2 r2 = *(float2*)&Rs[j * 36 + tx * 2];
            acc00 += p2.x * r2.x; acc01 += p2.x * r2.y;
            acc10 += p2.y * r2.x; acc11 += p2.y * r2.y;
        }
    }
    *(float2*)&T[hb + (size_t)(i0 + ty * 2) * 256 + k0 + tx * 2] = make_float2(acc00, acc01);
    *(float2*)&T[hb + (size_t)(i0 + ty * 2 + 1) * 256 + k0 + tx * 2] = make_float2(acc10, acc11);
    __syncthreads();  // before reusing Ps as reduction scratch
    float* red = Ps;  // [16][34]
    red[ty * 34 + tx * 2]     = q00 * acc00 + q10 * acc10;
    red[ty * 34 + tx * 2 + 1] = q01 * acc01 + q11 * acc11;
    __syncthreads();
    if (t < 32) {
        float s = 0.f;
#pragma unroll
        for (int m = 0; m < 16; m++) s += red[m * 34 + t];
        normp[h * 2048 + (i0 >> 5) * 256 + k0 + t] = s;
    }
}

// ---- K3: S = (Q rn) @ Rt. grid (8,8,4), prefetch dbuf. ----
__global__ __launch_bounds__(256) void k_S(const float* __restrict__ Q,
                                           const float* __restrict__ Rt,
                                           const float* __restrict__ normp,
                                           float* __restrict__ S) {
    __shared__ __align__(16) float As[1152];  // [k][i] (Q*rn transposed)
    __shared__ __align__(16) float Bs[1152];  // [k][j] (Rt natural)
    __shared__ float rn_s[256];
    int h = blockIdx.z, j0 = blockIdx.x * 32, i0 = blockIdx.y * 32;
    size_t hb = (size_t)h * 65536;
    int t = threadIdx.x, tx = t & 15, ty = t >> 4, r = t >> 3, g = t & 7;
    {
        float s = 0.f;
#pragma unroll
        for (int ib = 0; ib < 8; ib++) s += normp[h * 2048 + ib * 256 + t];
        rn_s[t] = 1.f / fmaxf(s, 1e-6f);
    }
    float4 a4 = *(const float4*)&Q[hb + (size_t)(i0 + r) * 256 + g * 4];
    float4 b4 = *(const float4*)&Rt[hb + (size_t)r * 256 + j0 + g * 4];
    __syncthreads();  // rn_s ready
    float a00 = 0, a01 = 0, a10 = 0, a11 = 0;
    for (int kc = 0; kc < 256; kc += 32) {
        As[(g * 4 + 0) * 36 + r] = a4.x * rn_s[kc + g * 4 + 0];
        As[(g * 4 + 1) * 36 + r] = a4.y * rn_s[kc + g * 4 + 1];
        As[(g * 4 + 2) * 36 + r] = a4.z * rn_s[kc + g * 4 + 2];
        As[(g * 4 + 3) * 36 + r] = a4.w * rn_s[kc + g * 4 + 3];
        *(float4*)&Bs[r * 36 + g * 4] = b4;
        __syncthreads();
        if (kc + 32 < 256) {
            a4 = *(const float4*)&Q[hb + (size_t)(i0 + r) * 256 + kc + 32 + g * 4];
            b4 = *(const float4*)&Rt[hb + (size_t)(kc + 32 + r) * 256 + j0 + g * 4];
        }
#pragma unroll
        for (int kk = 0; kk < 32; kk++) {
            float2 av = *(float2*)&As[kk * 36 + ty * 2];
            float2 bv = *(float2*)&Bs[kk * 36 + tx * 2];
            a00 += av.x * bv.x; a01 += av.x * bv.y;
            a10 += av.y * bv.x; a11 += av.y * bv.y;
        }
        __syncthreads();
    }
    *(float2*)&S[hb + (size_t)(i0 + ty * 2) * 256 + j0 + tx * 2] = make_float2(a00, a01);
    *(float2*)&S[hb + (size_t)(i0 + ty * 2 + 1) * 256 + j0 + tx * 2] = make_float2(a10, a11);
}

// ---- K4: x1=(P.*S)v, x2=(Q.*T.*rn)v, y=x1.*x2. grid (32,4). ----
__global__ __launch_bounds__(256) void k_x1x2(
    const float* __restrict__ P, const float* __restrict__ Q,
    const float* __restrict__ S, const float* __restrict__ T,
    const float* __restrict__ normp, const float* __restrict__ w,
    float* __restrict__ y) {
    int h = blockIdx.y;
    int i0 = blockIdx.x * 8;
    size_t hb = (size_t)h * 65536;
    __shared__ __align__(16) float wp[2048];    // [8][256]
    __shared__ __align__(16) float wq[2048];
    __shared__ __align__(16) float vls[8192];   // [256][32]
    __shared__ float rn_s[256];
    int t = threadIdx.x;
    {
        float s = 0.f;
#pragma unroll
        for (int ib = 0; ib < 8; ib++) s += normp[h * 2048 + ib * 256 + t];
        rn_s[t] = 1.f / fmaxf(s, 1e-6f);
    }
    __syncthreads();
#pragma unroll
    for (int m = 0; m < 2; m++) {
        int lin = (m * 256 + t) * 4;
        int rr = lin >> 8, jj = lin & 255;
        size_t o = hb + (size_t)(i0 + rr) * 256 + jj;
        float4 p4 = *(const float4*)&P[o];
        float4 s4 = *(const float4*)&S[o];
        float4 q4 = *(const float4*)&Q[o];
        float4 t4 = *(const float4*)&T[o];
        float4 wpv, wqv;
        wpv.x = p4.x * s4.x; wpv.y = p4.y * s4.y;
        wpv.z = p4.z * s4.z; wpv.w = p4.w * s4.w;
        wqv.x = q4.x * t4.x * rn_s[jj + 0]; wqv.y = q4.y * t4.y * rn_s[jj + 1];
        wqv.z = q4.z * t4.z * rn_s[jj + 2]; wqv.w = q4.w * t4.w * rn_s[jj + 3];
        *(float4*)&wp[rr * 256 + jj] = wpv;
        *(float4*)&wq[rr * 256 + jj] = wqv;
    }
#pragma unroll
    for (int m = 0; m < 8; m++) {
        int lin = (m * 256 + t) * 4;
        int jj = lin >> 5, dd = lin & 31;
        *(float4*)&vls[jj * 32 + dd] =
            *(const float4*)&w[(size_t)jj * 512 + 384 + h * 32 + dd];
    }
    __syncthreads();
    int d = t & 31, rl = t >> 5;
    float x1 = 0.f, x2 = 0.f;
#pragma unroll 8
    for (int j = 0; j < 256; j++) {
        float vv = vls[j * 32 + d];
        x1 += wp[rl * 256 + j] * vv;
        x2 += wq[rl * 256 + j] * vv;
    }
    y[(size_t)(i0 + rl) * 128 + h * 32 + d] = x1 * x2;
}

// ---- K5: out = y @ W_proj + b_proj. grid (4,8), prefetch dbuf. ----
__global__ __launch_bounds__(256) void k_proj(const float* __restrict__ y,
                                              const float* __restrict__ Wp,
                                              const float* __restrict__ bp,
                                              float* __restrict__ out) {
    __shared__ __align__(16) float As[1152];
    __shared__ __align__(16) float Bs[1152];
    int j0 = blockIdx.x * 32, i0 = blockIdx.y * 32;
    int t = threadIdx.x, tx = t & 15, ty = t >> 4, r = t >> 3, g = t & 7;
    float4 a4 = *(const float4*)&y[(size_t)(i0 + r) * 128 + g * 4];
    float4 b4 = *(const float4*)&Wp[(size_t)r * 128 + j0 + g * 4];
    float a00 = 0, a01 = 0, a10 = 0, a11 = 0;
    for (int kc = 0; kc < 128; kc += 32) {
        As[(g * 4 + 0) * 36 + r] = a4.x; As[(g * 4 + 1) * 36 + r] = a4.y;
        As[(g * 4 + 2) * 36 + r] = a4.z; As[(g * 4 + 3) * 36 + r] = a4.w;
        *(float4*)&Bs[r * 36 + g * 4] = b4;
        __syncthreads();
        if (kc + 32 < 128) {
            a4 = *(const float4*)&y[(size_t)(i0 + r) * 128 + kc + 32 + g * 4];
            b4 = *(const float4*)&Wp[(size_t)(kc + 32 + r) * 128 + j0 + g * 4];
        }
#pragma unroll
        for (int kk = 0; kk < 32; kk++) {
            float2 av = *(float2*)&As[kk * 36 + ty * 2];
            float2 bv = *(float2*)&Bs[kk * 36 + tx * 2];
            a00 += av.x * bv.x; a01 += av.x * bv.y;
            a10 += av.y * bv.x; a11 += av.y * bv.y;
        }
        __syncthreads();
    }
    float b0 = bp[j0 + tx * 2], b1 = bp[j0 + tx * 2 + 1];
    *(float2*)&out[(size_t)(i0 + ty * 2) * 128 + j0 + tx * 2] = make_float2(a00 + b0, a01 + b1);
    *(float2*)&out[(size_t)(i0 + ty * 2 + 1) * 128 + j0 + tx * 2] = make_float2(a10 + b0, a11 + b1);
}

extern "C" void kernel_launch(void* const* d_in, const int* in_sizes, int n_in,
                              void* d_out, int out_size, void* d_ws, size_t ws_size,
                              hipStream_t stream) {
    const float* x      = (const float*)d_in[0];
    const float* W_w    = (const float*)d_in[1];
    const float* W_proj = (const float*)d_in[2];
    const float* b_proj = (const float*)d_in[3];
    float* out = (float*)d_out;
    float* ws  = (float*)d_ws;

    float* w     = ws + OFF_W;
    float* P     = ws + OFF_P;
    float* Q     = ws + OFF_Q;
    float* Rt    = ws + OFF_RT;
    float* S     = ws + OFF_S;
    float* T     = ws + OFF_T;
    float* normp = ws + OFF_NORMP;
    float* y     = ws + OFF_Y;

    k_w<<<dim3(16, 8), 256, 0, stream>>>(x, W_w, w);
    k_T<<<dim3(8, 8, 4), 256, 0, stream>>>(w, P, Q, Rt, T, normp);
    k_S<<<dim3(8, 8, 4), 256, 0, stream>>>(Q, Rt, normp, S);
    k_x1x2<<<dim3(32, 4), 256, 0, stream>>>(P, Q, S, T, normp, w, y);
    k_proj<<<dim3(4, 8), 256, 0, stream>>>(y, W_proj, b_proj, out);
}

// Round 6
// 45.178 us; speedup vs baseline: 3.5372x; 1.0625x over previous
//
#include <hip/hip_runtime.h>
#include <hip/hip_bf16.h>

// B=1, NN=256, C=128, H=4, D=32 — O(N^3) factorization, 4 kernels.
//   w = x @ W_w (256x512); a,b,c,v head slices at col offsets 0,128,256,384
//   P = exp(s a b^T), Q = exp(s a c^T), R = exp(s b c^T)   (s = 1/sqrt(32))
//   k_T computes P,R on the fly per j-chunk, accumulates T = P R,
//       side-writes Q (all blocks), P (k0==0 blocks), R^T (i0==0 blocks),
//       and deterministic norm partials normp[h][i-block][k].
//   rn[k] = 1/clip(sum normp, 1e-6)
//   S[i,j] = sum_k (Q[i,k] rn[k]) Rt[k,j]
//   x1 = (P.*S) v ; x2 = (Q.*T.*rn) v ; y = x1.*x2
//   out = bias (init by k_w) + sum_h y_h @ W_proj[h-slice]  (atomics in k_x1x2)

constexpr size_t OFF_W     = 0;                    // 256*512
constexpr size_t OFF_P     = 131072;               // 4*65536 each
constexpr size_t OFF_Q     = OFF_P + 262144;
constexpr size_t OFF_RT    = OFF_Q + 262144;       // R^T: [h][k][j]
constexpr size_t OFF_S     = OFF_RT + 262144;
constexpr size_t OFF_T     = OFF_S + 262144;
constexpr size_t OFF_NORMP = OFF_T + 262144;       // 4*8*256
// workspace use ends at OFF_NORMP + 8192

// ---- K1: w = x(256x128) @ Ww(128x512), 32x32 tile, prefetch dbuf ----
//      also initializes out = bias (broadcast) for the atomic projection.
__global__ __launch_bounds__(256) void k_w(const float* __restrict__ x,
                                           const float* __restrict__ Ww,
                                           float* __restrict__ w,
                                           const float* __restrict__ bp,
                                           float* __restrict__ out) {
    __shared__ __align__(16) float As[1152];  // [k][i]
    __shared__ __align__(16) float Bs[1152];  // [k][j]
    int j0 = blockIdx.x * 32, i0 = blockIdx.y * 32;
    int t = threadIdx.x, tx = t & 15, ty = t >> 4, r = t >> 3, g = t & 7;
    {   // bias-init out: 128 blocks * 256 threads == 32768 == out elements
        int oidx = (blockIdx.y * 16 + blockIdx.x) * 256 + t;
        out[oidx] = bp[oidx & 127];
    }
    float4 a4 = *(const float4*)&x[(size_t)(i0 + r) * 128 + g * 4];
    float4 b4 = *(const float4*)&Ww[(size_t)r * 512 + j0 + g * 4];
    float a00 = 0, a01 = 0, a10 = 0, a11 = 0;
    for (int kc = 0; kc < 128; kc += 32) {
        As[(g * 4 + 0) * 36 + r] = a4.x; As[(g * 4 + 1) * 36 + r] = a4.y;
        As[(g * 4 + 2) * 36 + r] = a4.z; As[(g * 4 + 3) * 36 + r] = a4.w;
        *(float4*)&Bs[r * 36 + g * 4] = b4;
        __syncthreads();
        if (kc + 32 < 128) {
            a4 = *(const float4*)&x[(size_t)(i0 + r) * 128 + kc + 32 + g * 4];
            b4 = *(const float4*)&Ww[(size_t)(kc + 32 + r) * 512 + j0 + g * 4];
        }
#pragma unroll
        for (int kk = 0; kk < 32; kk++) {
            float2 av = *(float2*)&As[kk * 36 + ty * 2];
            float2 bv = *(float2*)&Bs[kk * 36 + tx * 2];
            a00 += av.x * bv.x; a01 += av.x * bv.y;
            a10 += av.y * bv.x; a11 += av.y * bv.y;
        }
        __syncthreads();
    }
    *(float2*)&w[(size_t)(i0 + ty * 2) * 512 + j0 + tx * 2] = make_float2(a00, a01);
    *(float2*)&w[(size_t)(i0 + ty * 2 + 1) * 512 + j0 + tx * 2] = make_float2(a10, a11);
}

// ---- K2: fused PQR + T + normp. grid (8,8,4). ----
__global__ __launch_bounds__(256) void k_T(const float* __restrict__ w,
                                           float* __restrict__ P,
                                           float* __restrict__ Q,
                                           float* __restrict__ Rt,
                                           float* __restrict__ T,
                                           float* __restrict__ normp) {
    __shared__ __align__(16) float aT[1152];  // [d][i]
    __shared__ __align__(16) float cT[1152];  // [d][k]
    __shared__ __align__(16) float bT[1152];  // [d][j]
    __shared__ __align__(16) float Ps[1152];  // [j][i]
    __shared__ __align__(16) float Rs[1152];  // [j][k]
    int h = blockIdx.z, k0 = blockIdx.x * 32, i0 = blockIdx.y * 32;
    size_t hb = (size_t)h * 65536;
    int t = threadIdx.x, tx = t & 15, ty = t >> 4, r = t >> 3, g = t & 7;
    const float sc = 0.17677669529663687f;

    float4 av = *(const float4*)&w[(size_t)(i0 + r) * 512 + h * 32 + g * 4];
    aT[(g * 4 + 0) * 36 + r] = av.x; aT[(g * 4 + 1) * 36 + r] = av.y;
    aT[(g * 4 + 2) * 36 + r] = av.z; aT[(g * 4 + 3) * 36 + r] = av.w;
    float4 cv = *(const float4*)&w[(size_t)(k0 + r) * 512 + 256 + h * 32 + g * 4];
    cT[(g * 4 + 0) * 36 + r] = cv.x; cT[(g * 4 + 1) * 36 + r] = cv.y;
    cT[(g * 4 + 2) * 36 + r] = cv.z; cT[(g * 4 + 3) * 36 + r] = cv.w;
    // prefetch first b chunk
    float4 bv = *(const float4*)&w[(size_t)r * 512 + 128 + h * 32 + g * 4];
    __syncthreads();

    // Q tile: i = 2ty+ii, k = 2tx+kk
    float dq00 = 0, dq01 = 0, dq10 = 0, dq11 = 0;
#pragma unroll
    for (int d = 0; d < 32; d++) {
        float2 a2 = *(float2*)&aT[d * 36 + ty * 2];
        float2 c2 = *(float2*)&cT[d * 36 + tx * 2];
        dq00 += a2.x * c2.x; dq01 += a2.x * c2.y;
        dq10 += a2.y * c2.x; dq11 += a2.y * c2.y;
    }
    float q00 = __expf(sc * dq00), q01 = __expf(sc * dq01);
    float q10 = __expf(sc * dq10), q11 = __expf(sc * dq11);
    *(float2*)&Q[hb + (size_t)(i0 + ty * 2) * 256 + k0 + tx * 2] = make_float2(q00, q01);
    *(float2*)&Q[hb + (size_t)(i0 + ty * 2 + 1) * 256 + k0 + tx * 2] = make_float2(q10, q11);

    const bool wP = (k0 == 0), wR = (i0 == 0);
    float acc00 = 0, acc01 = 0, acc10 = 0, acc11 = 0;
    for (int jc = 0; jc < 256; jc += 32) {
        bT[(g * 4 + 0) * 36 + r] = bv.x; bT[(g * 4 + 1) * 36 + r] = bv.y;
        bT[(g * 4 + 2) * 36 + r] = bv.z; bT[(g * 4 + 3) * 36 + r] = bv.w;
        __syncthreads();  // A: bT ready, prior Ps/Rs reads done
        if (jc + 32 < 256)
            bv = *(const float4*)&w[(size_t)(jc + 32 + r) * 512 + 128 + h * 32 + g * 4];
        float dp00 = 0, dp01 = 0, dp10 = 0, dp11 = 0;
        float dr00 = 0, dr01 = 0, dr10 = 0, dr11 = 0;
#pragma unroll
        for (int d = 0; d < 32; d++) {
            float2 b2 = *(float2*)&bT[d * 36 + ty * 2];
            float2 a2 = *(float2*)&aT[d * 36 + tx * 2];
            float2 c2 = *(float2*)&cT[d * 36 + tx * 2];
            dp00 += b2.x * a2.x; dp01 += b2.x * a2.y;
            dp10 += b2.y * a2.x; dp11 += b2.y * a2.y;
            dr00 += b2.x * c2.x; dr01 += b2.x * c2.y;
            dr10 += b2.y * c2.x; dr11 += b2.y * c2.y;
        }
        float p00 = __expf(sc * dp00), p01 = __expf(sc * dp01);
        float p10 = __expf(sc * dp10), p11 = __expf(sc * dp11);
        float r00 = __expf(sc * dr00), r01 = __expf(sc * dr01);
        float r10 = __expf(sc * dr10), r11 = __expf(sc * dr11);
        *(float2*)&Ps[(ty * 2 + 0) * 36 + tx * 2] = make_float2(p00, p01);
        *(float2*)&Ps[(ty * 2 + 1) * 36 + tx * 2] = make_float2(p10, p11);
        *(float2*)&Rs[(ty * 2 + 0) * 36 + tx * 2] = make_float2(r00, r01);
        *(float2*)&Rs[(ty * 2 + 1) * 36 + tx * 2] = make_float2(r10, r11);
        if (wP) {
            *(float2*)&P[hb + (size_t)(i0 + tx * 2 + 0) * 256 + jc + ty * 2] = make_float2(p00, p10);
            *(float2*)&P[hb + (size_t)(i0 + tx * 2 + 1) * 256 + jc + ty * 2] = make_float2(p01, p11);
        }
        if (wR) {
            *(float2*)&Rt[hb + (size_t)(k0 + tx * 2 + 0) * 256 + jc + ty * 2] = make_float2(r00, r10);
            *(float2*)&Rt[hb + (size_t)(k0 + tx * 2 + 1) * 256 + jc + ty * 2] = make_float2(r01, r11);
        }
        __syncthreads();  // B: Ps/Rs ready
#pragma unroll
        for (int j = 0; j < 32; j++) {
            float2 p2 = *(float2*)&Ps[j * 36 + ty * 2];
            float2 r2 = *(float2*)&Rs[j * 36 + tx * 2];
            acc00 += p2.x * r2.x; acc01 += p2.x * r2.y;
            acc10 += p2.y * r2.x; acc11 += p2.y * r2.y;
        }
    }
    *(float2*)&T[hb + (size_t)(i0 + ty * 2) * 256 + k0 + tx * 2] = make_float2(acc00, acc01);
    *(float2*)&T[hb + (size_t)(i0 + ty * 2 + 1) * 256 + k0 + tx * 2] = make_float2(acc10, acc11);
    __syncthreads();
    float* red = Ps;  // [16][34]
    red[ty * 34 + tx * 2]     = q00 * acc00 + q10 * acc10;
    red[ty * 34 + tx * 2 + 1] = q01 * acc01 + q11 * acc11;
    __syncthreads();
    if (t < 32) {
        float s = 0.f;
#pragma unroll
        for (int m = 0; m < 16; m++) s += red[m * 34 + t];
        normp[h * 2048 + (i0 >> 5) * 256 + k0 + t] = s;
    }
}

// ---- K3: S = (Q rn) @ Rt. grid (8,8,4), prefetch dbuf. ----
__global__ __launch_bounds__(256) void k_S(const float* __restrict__ Q,
                                           const float* __restrict__ Rt,
                                           const float* __restrict__ normp,
                                           float* __restrict__ S) {
    __shared__ __align__(16) float As[1152];  // [k][i] (Q*rn transposed)
    __shared__ __align__(16) float Bs[1152];  // [k][j] (Rt natural)
    __shared__ float rn_s[256];
    int h = blockIdx.z, j0 = blockIdx.x * 32, i0 = blockIdx.y * 32;
    size_t hb = (size_t)h * 65536;
    int t = threadIdx.x, tx = t & 15, ty = t >> 4, r = t >> 3, g = t & 7;
    {
        float s = 0.f;
#pragma unroll
        for (int ib = 0; ib < 8; ib++) s += normp[h * 2048 + ib * 256 + t];
        rn_s[t] = 1.f / fmaxf(s, 1e-6f);
    }
    float4 a4 = *(const float4*)&Q[hb + (size_t)(i0 + r) * 256 + g * 4];
    float4 b4 = *(const float4*)&Rt[hb + (size_t)r * 256 + j0 + g * 4];
    __syncthreads();  // rn_s ready
    float a00 = 0, a01 = 0, a10 = 0, a11 = 0;
    for (int kc = 0; kc < 256; kc += 32) {
        As[(g * 4 + 0) * 36 + r] = a4.x * rn_s[kc + g * 4 + 0];
        As[(g * 4 + 1) * 36 + r] = a4.y * rn_s[kc + g * 4 + 1];
        As[(g * 4 + 2) * 36 + r] = a4.z * rn_s[kc + g * 4 + 2];
        As[(g * 4 + 3) * 36 + r] = a4.w * rn_s[kc + g * 4 + 3];
        *(float4*)&Bs[r * 36 + g * 4] = b4;
        __syncthreads();
        if (kc + 32 < 256) {
            a4 = *(const float4*)&Q[hb + (size_t)(i0 + r) * 256 + kc + 32 + g * 4];
            b4 = *(const float4*)&Rt[hb + (size_t)(kc + 32 + r) * 256 + j0 + g * 4];
        }
#pragma unroll
        for (int kk = 0; kk < 32; kk++) {
            float2 av = *(float2*)&As[kk * 36 + ty * 2];
            float2 bv = *(float2*)&Bs[kk * 36 + tx * 2];
            a00 += av.x * bv.x; a01 += av.x * bv.y;
            a10 += av.y * bv.x; a11 += av.y * bv.y;
        }
        __syncthreads();
    }
    *(float2*)&S[hb + (size_t)(i0 + ty * 2) * 256 + j0 + tx * 2] = make_float2(a00, a01);
    *(float2*)&S[hb + (size_t)(i0 + ty * 2 + 1) * 256 + j0 + tx * 2] = make_float2(a10, a11);
}

// ---- K4: x1,x2,y + fused partial projection (atomicAdd into out). ----
// grid (32, 4): block = (8 rows, head h). out must be bias-initialized (k_w).
__global__ __launch_bounds__(256) void k_x1x2(
    const float* __restrict__ P, const float* __restrict__ Q,
    const float* __restrict__ S, const float* __restrict__ T,
    const float* __restrict__ normp, const float* __restrict__ w,
    const float* __restrict__ Wp, float* __restrict__ out) {
    int h = blockIdx.y;
    int i0 = blockIdx.x * 8;
    size_t hb = (size_t)h * 65536;
    __shared__ __align__(16) float wp[2048];    // [8][256]
    __shared__ __align__(16) float wq[2048];
    __shared__ __align__(16) float vls[8192];   // [256][32]
    __shared__ float rn_s[256];
    int t = threadIdx.x;
    {
        float s = 0.f;
#pragma unroll
        for (int ib = 0; ib < 8; ib++) s += normp[h * 2048 + ib * 256 + t];
        rn_s[t] = 1.f / fmaxf(s, 1e-6f);
    }
    __syncthreads();
#pragma unroll
    for (int m = 0; m < 2; m++) {
        int lin = (m * 256 + t) * 4;
        int rr = lin >> 8, jj = lin & 255;
        size_t o = hb + (size_t)(i0 + rr) * 256 + jj;
        float4 p4 = *(const float4*)&P[o];
        float4 s4 = *(const float4*)&S[o];
        float4 q4 = *(const float4*)&Q[o];
        float4 t4 = *(const float4*)&T[o];
        float4 wpv, wqv;
        wpv.x = p4.x * s4.x; wpv.y = p4.y * s4.y;
        wpv.z = p4.z * s4.z; wpv.w = p4.w * s4.w;
        wqv.x = q4.x * t4.x * rn_s[jj + 0]; wqv.y = q4.y * t4.y * rn_s[jj + 1];
        wqv.z = q4.z * t4.z * rn_s[jj + 2]; wqv.w = q4.w * t4.w * rn_s[jj + 3];
        *(float4*)&wp[rr * 256 + jj] = wpv;
        *(float4*)&wq[rr * 256 + jj] = wqv;
    }
#pragma unroll
    for (int m = 0; m < 8; m++) {
        int lin = (m * 256 + t) * 4;
        int jj = lin >> 5, dd = lin & 31;
        *(float4*)&vls[jj * 32 + dd] =
            *(const float4*)&w[(size_t)jj * 512 + 384 + h * 32 + dd];
    }
    __syncthreads();
    int d = t & 31, rl = t >> 5;
    float x1 = 0.f, x2 = 0.f;
#pragma unroll 8
    for (int j = 0; j < 256; j++) {
        float vv = vls[j * 32 + d];
        x1 += wp[rl * 256 + j] * vv;
        x2 += wq[rl * 256 + j] * vv;
    }
    float yv = x1 * x2;  // y[i0+rl][h*32+d]
    __syncthreads();     // done reading wp/vls; reuse as ys / Wps
    float* ys = wp;      // [8][33]
    float* Wps = vls;    // [32][128]
    ys[rl * 33 + d] = yv;
#pragma unroll
    for (int m = 0; m < 4; m++) {
        int idx = m * 256 + t;        // float4 index, 1024 total
        int lin = idx * 4;
        int k = lin >> 7, n = lin & 127;
        *(float4*)&Wps[k * 128 + n] =
            *(const float4*)&Wp[(size_t)(h * 32 + k) * 128 + n];
    }
    __syncthreads();
    int n = t & 127, ti = t >> 7;     // ti in {0,1}; rows ti, ti+2, ti+4, ti+6
    float acc0 = 0, acc1 = 0, acc2 = 0, acc3 = 0;
#pragma unroll
    for (int k = 0; k < 32; k++) {
        float wv = Wps[k * 128 + n];
        acc0 += ys[(ti + 0) * 33 + k] * wv;
        acc1 += ys[(ti + 2) * 33 + k] * wv;
        acc2 += ys[(ti + 4) * 33 + k] * wv;
        acc3 += ys[(ti + 6) * 33 + k] * wv;
    }
    atomicAdd(&out[(size_t)(i0 + ti + 0) * 128 + n], acc0);
    atomicAdd(&out[(size_t)(i0 + ti + 2) * 128 + n], acc1);
    atomicAdd(&out[(size_t)(i0 + ti + 4) * 128 + n], acc2);
    atomicAdd(&out[(size_t)(i0 + ti + 6) * 128 + n], acc3);
}

extern "C" void kernel_launch(void* const* d_in, const int* in_sizes, int n_in,
                              void* d_out, int out_size, void* d_ws, size_t ws_size,
                              hipStream_t stream) {
    const float* x      = (const float*)d_in[0];
    const float* W_w    = (const float*)d_in[1];
    const float* W_proj = (const float*)d_in[2];
    const float* b_proj = (const float*)d_in[3];
    float* out = (float*)d_out;
    float* ws  = (float*)d_ws;

    float* w     = ws + OFF_W;
    float* P     = ws + OFF_P;
    float* Q     = ws + OFF_Q;
    float* Rt    = ws + OFF_RT;
    float* S     = ws + OFF_S;
    float* T     = ws + OFF_T;
    float* normp = ws + OFF_NORMP;

    k_w<<<dim3(16, 8), 256, 0, stream>>>(x, W_w, w, b_proj, out);
    k_T<<<dim3(8, 8, 4), 256, 0, stream>>>(w, P, Q, Rt, T, normp);
    k_S<<<dim3(8, 8, 4), 256, 0, stream>>>(Q, Rt, normp, S);
    k_x1x2<<<dim3(32, 4), 256, 0, stream>>>(P, Q, S, T, normp, w, W_proj, out);
}